// Round 11
// baseline (180.013 us; speedup 1.0000x reference)
//
#include <hip/hip_runtime.h>

// Problem constants
#define T_ 128
#define B_ 64
#define NH_ 64
#define NC_ 10

__device__ __forceinline__ float sigmoid_f(float x) {
    return 1.0f / (1.0f + __expf(-x));
}
__device__ __forceinline__ float tanh_f(float x) {
    return 1.0f - 2.0f / (1.0f + __expf(2.0f * x));
}
// 4-wide partial dot accumulate (inline fn, not macro — R8 lesson)
__device__ __forceinline__ void dot4(const float4 a, const float4 v,
                                     float& p0, float& p1, float& p2, float& p3) {
    p0 = fmaf(a.x, v.x, p0);
    p1 = fmaf(a.y, v.y, p1);
    p2 = fmaf(a.z, v.z, p2);
    p3 = fmaf(a.w, v.w, p3);
}

// Broadcast h from lane (32*s + J) of own 32-lane group via ds_swizzle
// (BitMode: and=0, or=J, xor=0; 5-bit masks act within 32-lane groups, so
// each k-half group broadcasts from ITS half — no LDS array, no barrier).
// J must be a literal (builtin requires ICE).
#define SWZF(J, WW, PP) { \
    int swz_ = __builtin_amdgcn_ds_swizzle(h_bits, (J) << 5); \
    PP = fmaf((WW), __int_as_float(swz_), PP); }

// ---------------------------------------------------------------------------
// Kernel 1: per-frame 3x3 VALID conv -> sigmoid(logit-thr) -> spatial mean.
// grid = 8192, 256 threads. (unchanged)
// ---------------------------------------------------------------------------
#define IMP 68
__global__ __launch_bounds__(256) void conv_feat(const float* __restrict__ img,
                                                 const float* __restrict__ cw,
                                                 const float* __restrict__ cb,
                                                 const float* __restrict__ thr,
                                                 float* __restrict__ feat) {
    __shared__ __align__(16) float im[64 * IMP];
    __shared__ float wsum[4];
    const int tid = threadIdx.x;
    const float* src = img + (size_t)blockIdx.x * 4096;
#pragma unroll
    for (int i = 0; i < 4; i++) {
        const int idx = i * 256 + tid;
        const int row = idx >> 4, c4 = idx & 15;
        *(float4*)&im[row * IMP + c4 * 4] = *(const float4*)&src[idx * 4];
    }
    const float w0 = cw[0], w1 = cw[1], w2 = cw[2], w3 = cw[3], w4 = cw[4],
                w5 = cw[5], w6 = cw[6], w7 = cw[7], w8 = cw[8];
    const float bias = cb[0] - thr[0];
    __syncthreads();

    const int r  = tid >> 2;
    const int c0 = (tid & 3) * 16;
    float sum = 0.0f;
    if (r < 62) {
        const int ncols = (c0 == 48) ? 14 : 16;
        float acc[16];
#pragma unroll
        for (int x = 0; x < 16; x++) acc[x] = bias;
#pragma unroll
        for (int dr = 0; dr < 3; dr++) {
            float rb[20];
#pragma unroll
            for (int j = 0; j < 5; j++) {
                float4 v = *(const float4*)&im[(r + dr) * IMP + c0 + j * 4];
                rb[j * 4 + 0] = v.x; rb[j * 4 + 1] = v.y;
                rb[j * 4 + 2] = v.z; rb[j * 4 + 3] = v.w;
            }
            const float k0 = (dr == 0) ? w0 : (dr == 1) ? w3 : w6;
            const float k1 = (dr == 0) ? w1 : (dr == 1) ? w4 : w7;
            const float k2 = (dr == 0) ? w2 : (dr == 1) ? w5 : w8;
#pragma unroll
            for (int x = 0; x < 16; x++) {
                acc[x] = fmaf(rb[x], k0, acc[x]);
                acc[x] = fmaf(rb[x + 1], k1, acc[x]);
                acc[x] = fmaf(rb[x + 2], k2, acc[x]);
            }
        }
#pragma unroll
        for (int x = 0; x < 16; x++)
            if (x < ncols) sum += sigmoid_f(acc[x]);
    }
#pragma unroll
    for (int off = 32; off >= 1; off >>= 1) sum += __shfl_down(sum, off, 64);
    const int wv = tid >> 6, ln = tid & 63;
    if (ln == 0) wsum[wv] = sum;
    __syncthreads();
    if (tid == 0)
        feat[blockIdx.x] = (wsum[0] + wsum[1] + wsum[2] + wsum[3]) * (1.0f / 3844.0f);
}

// ---------------------------------------------------------------------------
// Kernel 2: fold fc+lw per gate (unchanged). grid = 4, 256 threads.
// ---------------------------------------------------------------------------
struct FuseArgs {
    const float* fcw[4];
    const float* fcb[4];
    const float* lw[4];
    const float* lb[4];
};

__global__ __launch_bounds__(256) void fuse_kernel(FuseArgs a, float* __restrict__ Aall,
                                                   float* __restrict__ Vall,
                                                   float* __restrict__ Call) {
    const int g = blockIdx.x;
    const float* fcw = a.fcw[g];
    const float* fcb = a.fcb[g];
    const float* lw  = a.lw[g];
    const float* lb  = a.lb[g];
    __shared__ float fcs[64 * 65];
    __shared__ float fbs[64];
    for (int i = threadIdx.x; i < 64 * 65; i += 256) fcs[i] = fcw[i];
    if (threadIdx.x < 64) fbs[threadIdx.x] = fcb[threadIdx.x];
    __syncthreads();

    const int n = threadIdx.x >> 2;
    const int j0 = (threadIdx.x & 3) * 16;
    float lrow[64];
#pragma unroll
    for (int k = 0; k < 64; k++) lrow[k] = lw[n * 64 + k];

    for (int j = j0; j < j0 + 16; j++) {
        float s = 0.0f;
#pragma unroll
        for (int k = 0; k < 64; k++) s = fmaf(lrow[k], fcs[k * 65 + j + 1], s);
        Aall[(g * 64 + n) * 64 + j] = s;
    }
    if ((threadIdx.x & 3) == 0) {
        float sv = 0.0f, sc = 0.0f;
#pragma unroll
        for (int k = 0; k < 64; k++) {
            sv = fmaf(lrow[k], fcs[k * 65], sv);
            sc = fmaf(lrow[k], fbs[k], sc);
        }
        Vall[g * 64 + n] = sv;
        Call[g * 64 + n] = sc + lb[n];
    }
}

// ---------------------------------------------------------------------------
// Kernel 3: recurrence + fused classifier, SPLIT-K=2 with REGISTER h.
// 64 blocks x 512 threads = 8 waves (R9 base, best measured: 2190 cyc/step).
// wave = (gate g, n-half nh); lane = (n&31) | (k-half s)<<5.
// NEW vs R9: cell state is owned by k-range — thread tracks cx/h for
// n' = s*32+(lane&31) in REGISTERS; stage-1's h[k] comes from its own
// 32-lane group via ds_swizzle broadcast. This deletes the h LDS array,
// its write+drain+read, and barrier 3 (~350-400 cyc of the step).
// 2 barriers/step remain (q and acts exchanges, irreducibly cross-wave).
// ---------------------------------------------------------------------------
__global__ __launch_bounds__(512, 1) void recur(
    const float* __restrict__ feat, const float* __restrict__ Aall,
    const float* __restrict__ Vall, const float* __restrict__ Call,
    const float* __restrict__ ew_f, const float* __restrict__ eb_f,
    const float* __restrict__ ew_i, const float* __restrict__ eb_i,
    const float* __restrict__ ew_u, const float* __restrict__ eb_u,
    const float* __restrict__ ew_o, const float* __restrict__ eb_o,
    const float* __restrict__ cls_w, const float* __restrict__ cls_b,
    float* __restrict__ out) {
    const int b = blockIdx.x;
    const int tid = threadIdx.x;
    const int wave = tid >> 6;
    const int g = wave >> 1;               // gate 0..3
    const int nh = wave & 1;               // n-half 0..1
    const int lane = tid & 63;
    const int s = lane >> 5;               // k-half 0..1
    const int n = nh * 32 + (lane & 31);   // owned OUTPUT index (q, acts)
    const int np = s * 32 + (lane & 31);   // owned CELL index (cx, h)
    const int gn = g * 64 + n;
    const float* ew  = (g == 0) ? ew_f : (g == 1) ? ew_i : (g == 2) ? ew_u : ew_o;
    const float* ebp = (g == 0) ? eb_f : (g == 1) ? eb_i : (g == 2) ? eb_u : eb_o;

    // weight slices (32 floats each); per-step reloads proven free (R4/R6)
    const float4* ap = (const float4*)&Aall[gn * 64 + s * 32];
    const float4* ep = (const float4*)&ew[n * 64 + s * 32];
    const float4 wa0 = ap[0], wa1 = ap[1], wa2 = ap[2], wa3 = ap[3];
    const float4 wa4 = ap[4], wa5 = ap[5], wa6 = ap[6], wa7 = ap[7];
    const float4 we0 = ep[0], we1 = ep[1], we2 = ep[2], we3 = ep[3];
    const float4 we4 = ep[4], we5 = ep[5], we6 = ep[6], we7 = ep[7];
    const float vj = Vall[gn], cj = Call[gn], ebj = ebp[n];

    __shared__ __align__(16) float qsh[4][64];
    __shared__ __align__(16) float acts[2][4][64];
    __shared__ __align__(16) float xts[T_];
    __shared__ float hist[T_ * 65];              // 33.3 KB
    __shared__ float cwts[NC_ * 65 + NC_];

    for (int i = tid; i < T_; i += 512) xts[i] = feat[b * T_ + i];
    for (int i = tid; i < NC_ * 64; i += 512) {
        int c = i >> 6, k = i & 63;
        cwts[c * 65 + k] = cls_w[i];
    }
    if (tid < NC_) cwts[NC_ * 65 + tid] = cls_b[tid];
    float cx = 0.0f, h_own = 0.0f;   // cell state for unit np, in registers
    __syncthreads();

    const float4* qp = (const float4*)&qsh[g][s * 32];

    for (int t = 0; t < T_; t++) {
        const float xt = xts[t];

        // ---- stage 1: q = tanh(xt*v + h @ A^T + c) ----
        // h[s*32+j] broadcast from lane j of own 32-lane group (register h)
        const int h_bits = __float_as_int(h_own);
        float p0 = 0, p1 = 0, p2 = 0, p3 = 0;
        SWZF(0,  wa0.x, p0) SWZF(1,  wa0.y, p1) SWZF(2,  wa0.z, p2) SWZF(3,  wa0.w, p3)
        SWZF(4,  wa1.x, p0) SWZF(5,  wa1.y, p1) SWZF(6,  wa1.z, p2) SWZF(7,  wa1.w, p3)
        SWZF(8,  wa2.x, p0) SWZF(9,  wa2.y, p1) SWZF(10, wa2.z, p2) SWZF(11, wa2.w, p3)
        SWZF(12, wa3.x, p0) SWZF(13, wa3.y, p1) SWZF(14, wa3.z, p2) SWZF(15, wa3.w, p3)
        SWZF(16, wa4.x, p0) SWZF(17, wa4.y, p1) SWZF(18, wa4.z, p2) SWZF(19, wa4.w, p3)
        SWZF(20, wa5.x, p0) SWZF(21, wa5.y, p1) SWZF(22, wa5.z, p2) SWZF(23, wa5.w, p3)
        SWZF(24, wa6.x, p0) SWZF(25, wa6.y, p1) SWZF(26, wa6.z, p2) SWZF(27, wa6.w, p3)
        SWZF(28, wa7.x, p0) SWZF(29, wa7.y, p1) SWZF(30, wa7.z, p2) SWZF(31, wa7.w, p3)
        float p = (p0 + p1) + (p2 + p3);
        p += __shfl_xor(p, 32, 64);                 // combine the two k-halves
        const float q = tanh_f(fmaf(xt, vj, cj) + p);
        if (s == 0) qsh[g][n] = q;
        __syncthreads();                            // barrier 1 (q exchange)

        // ---- stage 2: z = q * sigmoid(q @ ew^T + eb), split-K over s ----
        p0 = 0; p1 = 0; p2 = 0; p3 = 0;
        {
            float4 v0 = qp[0], v1 = qp[1], v2 = qp[2], v3 = qp[3];
            float4 v4 = qp[4], v5 = qp[5], v6 = qp[6], v7 = qp[7];
            dot4(we0, v0, p0, p1, p2, p3);
            dot4(we1, v1, p0, p1, p2, p3);
            dot4(we2, v2, p0, p1, p2, p3);
            dot4(we3, v3, p0, p1, p2, p3);
            dot4(we4, v4, p0, p1, p2, p3);
            dot4(we5, v5, p0, p1, p2, p3);
            dot4(we6, v6, p0, p1, p2, p3);
            dot4(we7, v7, p0, p1, p2, p3);
        }
        p = (p0 + p1) + (p2 + p3);
        p += __shfl_xor(p, 32, 64);
        const float z = q * sigmoid_f(p + ebj);
        const float act = (g == 2) ? tanh_f(z) : sigmoid_f(z);
        if (s == 0) acts[t & 1][g][n] = act;
        __syncthreads();                            // barrier 2 (acts exchange)

        // ---- cell update for np (k-range ownership), pure registers ----
        const float ff = acts[t & 1][0][np];
        const float ii = acts[t & 1][1][np];
        const float uu = acts[t & 1][2][np];
        const float oo = acts[t & 1][3][np];
        cx = fmaf(ff, cx, ii * uu);
        h_own = oo * tanh_f(cx);
        if (wave == 0) hist[t * 65 + np] = h_own;   // 64 lanes cover n=0..63
        // no barrier 3: next stage 1 uses h_own via intra-wave swizzle only
    }
    __syncthreads();  // hist complete

    // fused classifier: T_*NC_ = 1280 outputs over 512 threads
#pragma unroll
    for (int j = 0; j < 3; j++) {
        const int o = j * 512 + tid;
        if (o < T_ * NC_) {
            const int r = o / 10;
            const int c = o - r * 10;
            float sacc = cwts[NC_ * 65 + c];
#pragma unroll 16
            for (int k = 0; k < 64; k++)
                sacc = fmaf(hist[r * 65 + k], cwts[c * 65 + k], sacc);
            out[((size_t)r * B_ + b) * NC_ + c] = sacc;
        }
    }
}

// ---------------------------------------------------------------------------
extern "C" void kernel_launch(void* const* d_in, const int* in_sizes, int n_in,
                              void* d_out, int out_size, void* d_ws, size_t ws_size,
                              hipStream_t stream) {
    const float* images = (const float*)d_in[0];
    const float* thr    = (const float*)d_in[1];
    const float* convw  = (const float*)d_in[2];
    const float* convb  = (const float*)d_in[3];
    const float* fcw[4]; const float* fcb[4]; const float* lw[4]; const float* lb[4];
    const float* ew[4];  const float* eb[4];
    for (int g = 0; g < 4; g++) {
        int base = 4 + g * 6;
        fcw[g] = (const float*)d_in[base + 0];
        fcb[g] = (const float*)d_in[base + 1];
        lw[g]  = (const float*)d_in[base + 2];
        lb[g]  = (const float*)d_in[base + 3];
        ew[g]  = (const float*)d_in[base + 4];
        eb[g]  = (const float*)d_in[base + 5];
    }
    const float* clsw = (const float*)d_in[28];
    const float* clsb = (const float*)d_in[29];

    float* ws   = (float*)d_ws;
    float* feat = ws;            // 8192 floats
    float* Aall = ws + 8192;     // 16384 floats
    float* Vall = ws + 24576;    // 256
    float* Call = ws + 24832;    // 256

    conv_feat<<<8192, 256, 0, stream>>>(images, convw, convb, thr, feat);

    FuseArgs fa;
    for (int g = 0; g < 4; g++) {
        fa.fcw[g] = fcw[g]; fa.fcb[g] = fcb[g];
        fa.lw[g] = lw[g];   fa.lb[g] = lb[g];
    }
    fuse_kernel<<<4, 256, 0, stream>>>(fa, Aall, Vall, Call);

    recur<<<B_, 512, 0, stream>>>(feat, Aall, Vall, Call,
                                  ew[0], eb[0], ew[1], eb[1],
                                  ew[2], eb[2], ew[3], eb[3],
                                  clsw, clsb, (float*)d_out);
}

// Round 12
// 174.226 us; speedup vs baseline: 1.0332x; 1.0332x over previous
//
#include <hip/hip_runtime.h>

// Problem constants
#define T_ 128
#define B_ 64
#define NH_ 64
#define NC_ 10

__device__ __forceinline__ float sigmoid_f(float x) {
    return 1.0f / (1.0f + __expf(-x));
}
__device__ __forceinline__ float tanh_f(float x) {
    return 1.0f - 2.0f / (1.0f + __expf(2.0f * x));
}
// 4-wide partial dot accumulate (inline fn, not macro — R8 lesson)
__device__ __forceinline__ void dot4(const float4 a, const float4 v,
                                     float& p0, float& p1, float& p2, float& p3) {
    p0 = fmaf(a.x, v.x, p0);
    p1 = fmaf(a.y, v.y, p1);
    p2 = fmaf(a.z, v.z, p2);
    p3 = fmaf(a.w, v.w, p3);
}

// ---------------------------------------------------------------------------
// Kernel 1: per-frame 3x3 VALID conv -> sigmoid(logit-thr) -> spatial mean.
// grid = 8192, 256 threads. (unchanged)
// ---------------------------------------------------------------------------
#define IMP 68
__global__ __launch_bounds__(256) void conv_feat(const float* __restrict__ img,
                                                 const float* __restrict__ cw,
                                                 const float* __restrict__ cb,
                                                 const float* __restrict__ thr,
                                                 float* __restrict__ feat) {
    __shared__ __align__(16) float im[64 * IMP];
    __shared__ float wsum[4];
    const int tid = threadIdx.x;
    const float* src = img + (size_t)blockIdx.x * 4096;
#pragma unroll
    for (int i = 0; i < 4; i++) {
        const int idx = i * 256 + tid;
        const int row = idx >> 4, c4 = idx & 15;
        *(float4*)&im[row * IMP + c4 * 4] = *(const float4*)&src[idx * 4];
    }
    const float w0 = cw[0], w1 = cw[1], w2 = cw[2], w3 = cw[3], w4 = cw[4],
                w5 = cw[5], w6 = cw[6], w7 = cw[7], w8 = cw[8];
    const float bias = cb[0] - thr[0];
    __syncthreads();

    const int r  = tid >> 2;
    const int c0 = (tid & 3) * 16;
    float sum = 0.0f;
    if (r < 62) {
        const int ncols = (c0 == 48) ? 14 : 16;
        float acc[16];
#pragma unroll
        for (int x = 0; x < 16; x++) acc[x] = bias;
#pragma unroll
        for (int dr = 0; dr < 3; dr++) {
            float rb[20];
#pragma unroll
            for (int j = 0; j < 5; j++) {
                float4 v = *(const float4*)&im[(r + dr) * IMP + c0 + j * 4];
                rb[j * 4 + 0] = v.x; rb[j * 4 + 1] = v.y;
                rb[j * 4 + 2] = v.z; rb[j * 4 + 3] = v.w;
            }
            const float k0 = (dr == 0) ? w0 : (dr == 1) ? w3 : w6;
            const float k1 = (dr == 0) ? w1 : (dr == 1) ? w4 : w7;
            const float k2 = (dr == 0) ? w2 : (dr == 1) ? w5 : w8;
#pragma unroll
            for (int x = 0; x < 16; x++) {
                acc[x] = fmaf(rb[x], k0, acc[x]);
                acc[x] = fmaf(rb[x + 1], k1, acc[x]);
                acc[x] = fmaf(rb[x + 2], k2, acc[x]);
            }
        }
#pragma unroll
        for (int x = 0; x < 16; x++)
            if (x < ncols) sum += sigmoid_f(acc[x]);
    }
#pragma unroll
    for (int off = 32; off >= 1; off >>= 1) sum += __shfl_down(sum, off, 64);
    const int wv = tid >> 6, ln = tid & 63;
    if (ln == 0) wsum[wv] = sum;
    __syncthreads();
    if (tid == 0)
        feat[blockIdx.x] = (wsum[0] + wsum[1] + wsum[2] + wsum[3]) * (1.0f / 3844.0f);
}

// ---------------------------------------------------------------------------
// Kernel 2: fold fc+lw per gate (unchanged). grid = 4, 256 threads.
// ---------------------------------------------------------------------------
struct FuseArgs {
    const float* fcw[4];
    const float* fcb[4];
    const float* lw[4];
    const float* lb[4];
};

__global__ __launch_bounds__(256) void fuse_kernel(FuseArgs a, float* __restrict__ Aall,
                                                   float* __restrict__ Vall,
                                                   float* __restrict__ Call) {
    const int g = blockIdx.x;
    const float* fcw = a.fcw[g];
    const float* fcb = a.fcb[g];
    const float* lw  = a.lw[g];
    const float* lb  = a.lb[g];
    __shared__ float fcs[64 * 65];
    __shared__ float fbs[64];
    for (int i = threadIdx.x; i < 64 * 65; i += 256) fcs[i] = fcw[i];
    if (threadIdx.x < 64) fbs[threadIdx.x] = fcb[threadIdx.x];
    __syncthreads();

    const int n = threadIdx.x >> 2;
    const int j0 = (threadIdx.x & 3) * 16;
    float lrow[64];
#pragma unroll
    for (int k = 0; k < 64; k++) lrow[k] = lw[n * 64 + k];

    for (int j = j0; j < j0 + 16; j++) {
        float s = 0.0f;
#pragma unroll
        for (int k = 0; k < 64; k++) s = fmaf(lrow[k], fcs[k * 65 + j + 1], s);
        Aall[(g * 64 + n) * 64 + j] = s;
    }
    if ((threadIdx.x & 3) == 0) {
        float sv = 0.0f, sc = 0.0f;
#pragma unroll
        for (int k = 0; k < 64; k++) {
            sv = fmaf(lrow[k], fcs[k * 65], sv);
            sc = fmaf(lrow[k], fbs[k], sc);
        }
        Vall[g * 64 + n] = sv;
        Call[g * 64 + n] = sc + lb[n];
    }
}

// ---------------------------------------------------------------------------
// Kernel 3: recurrence + fused classifier — LDS-instruction-minimized.
// 64 blocks x 256 threads = 4 waves; wave = gate g.
// lane = (n&31) | (s<<5): thread owns outputs n0=(lane&31), n1=n0+32 for
// gate g with k-slice [s*32, s*32+32)  -> broadcast reads amortize over 2
// outputs (8 b128/wave/stage, half of R9's per-output cost).
// q exchange is OWN-WAVE (wave g produces+consumes q[g][*]): same-wave DS
// ops are hardware-ordered, no barrier, no asm waits. Cell update is done
// redundantly by every wave (np = lane), h kept in per-wave private LDS.
// ONE barrier per step (acts, double-buffered, transposed [64][4] so the
// cell update reads a single b128).
// ---------------------------------------------------------------------------
__global__ __launch_bounds__(256, 1) void recur(
    const float* __restrict__ feat, const float* __restrict__ Aall,
    const float* __restrict__ Vall, const float* __restrict__ Call,
    const float* __restrict__ ew_f, const float* __restrict__ eb_f,
    const float* __restrict__ ew_i, const float* __restrict__ eb_i,
    const float* __restrict__ ew_u, const float* __restrict__ eb_u,
    const float* __restrict__ ew_o, const float* __restrict__ eb_o,
    const float* __restrict__ cls_w, const float* __restrict__ cls_b,
    float* __restrict__ out) {
    const int b = blockIdx.x;
    const int tid = threadIdx.x;
    const int g = tid >> 6;              // gate = wave
    const int lane = tid & 63;
    const int s = lane >> 5;             // k-half
    const int nb = lane & 31;
    const int n0 = nb, n1 = nb + 32;     // two owned outputs
    const int np = lane;                 // owned cell index
    const float* ew  = (g == 0) ? ew_f : (g == 1) ? ew_i : (g == 2) ? ew_u : ew_o;
    const float* ebp = (g == 0) ? eb_f : (g == 1) ? eb_i : (g == 2) ? eb_u : eb_o;

    // weight slices: 2 outputs x 32 k for each stage (32 float4 total)
    const float4* ap0 = (const float4*)&Aall[(g * 64 + n0) * 64 + s * 32];
    const float4* ap1 = (const float4*)&Aall[(g * 64 + n1) * 64 + s * 32];
    const float4* ep0 = (const float4*)&ew[n0 * 64 + s * 32];
    const float4* ep1 = (const float4*)&ew[n1 * 64 + s * 32];
    const float4 wa00 = ap0[0], wa01 = ap0[1], wa02 = ap0[2], wa03 = ap0[3];
    const float4 wa04 = ap0[4], wa05 = ap0[5], wa06 = ap0[6], wa07 = ap0[7];
    const float4 wa10 = ap1[0], wa11 = ap1[1], wa12 = ap1[2], wa13 = ap1[3];
    const float4 wa14 = ap1[4], wa15 = ap1[5], wa16 = ap1[6], wa17 = ap1[7];
    const float4 we00 = ep0[0], we01 = ep0[1], we02 = ep0[2], we03 = ep0[3];
    const float4 we04 = ep0[4], we05 = ep0[5], we06 = ep0[6], we07 = ep0[7];
    const float4 we10 = ep1[0], we11 = ep1[1], we12 = ep1[2], we13 = ep1[3];
    const float4 we14 = ep1[4], we15 = ep1[5], we16 = ep1[6], we17 = ep1[7];
    const float vj0 = Vall[g * 64 + n0], cj0 = Call[g * 64 + n0], ebj0 = ebp[n0];
    const float vj1 = Vall[g * 64 + n1], cj1 = Call[g * 64 + n1], ebj1 = ebp[n1];

    __shared__ __align__(16) float h_lds[4][64];     // per-wave private h copy
    __shared__ __align__(16) float q_lds[4][64];     // per-wave private q
    __shared__ __align__(16) float acts_t[2][64][4]; // transposed, dbl-buffered
    __shared__ __align__(16) float xts[T_];
    __shared__ float hist[T_ * 65];                  // 33.3 KB
    __shared__ float cwts[NC_ * 65 + NC_];

    for (int i = tid; i < T_; i += 256) xts[i] = feat[b * T_ + i];
    for (int i = tid; i < NC_ * 64; i += 256) {
        int c = i >> 6, k = i & 63;
        cwts[c * 65 + k] = cls_w[i];
    }
    if (tid < NC_) cwts[NC_ * 65 + tid] = cls_b[tid];
    h_lds[g][np] = 0.0f;                 // each wave zeroes its own copy
    float cx = 0.0f;                     // cell state for np, per thread
    __syncthreads();

    const float4* hp = (const float4*)&h_lds[g][s * 32];
    const float4* qp = (const float4*)&q_lds[g][s * 32];

    for (int t = 0; t < T_; t++) {
        const float xt = xts[t];

        // ---- stage 1: q = tanh(xt*v + h @ A^T + c), 2 outputs/thread ----
        float a00 = 0, a01 = 0, a02 = 0, a03 = 0;
        float a10 = 0, a11 = 0, a12 = 0, a13 = 0;
        {
            float4 v0 = hp[0], v1 = hp[1], v2 = hp[2], v3 = hp[3];
            float4 v4 = hp[4], v5 = hp[5], v6 = hp[6], v7 = hp[7];
            dot4(wa00, v0, a00, a01, a02, a03); dot4(wa10, v0, a10, a11, a12, a13);
            dot4(wa01, v1, a00, a01, a02, a03); dot4(wa11, v1, a10, a11, a12, a13);
            dot4(wa02, v2, a00, a01, a02, a03); dot4(wa12, v2, a10, a11, a12, a13);
            dot4(wa03, v3, a00, a01, a02, a03); dot4(wa13, v3, a10, a11, a12, a13);
            dot4(wa04, v4, a00, a01, a02, a03); dot4(wa14, v4, a10, a11, a12, a13);
            dot4(wa05, v5, a00, a01, a02, a03); dot4(wa15, v5, a10, a11, a12, a13);
            dot4(wa06, v6, a00, a01, a02, a03); dot4(wa16, v6, a10, a11, a12, a13);
            dot4(wa07, v7, a00, a01, a02, a03); dot4(wa17, v7, a10, a11, a12, a13);
        }
        float pa = (a00 + a01) + (a02 + a03);
        float pb = (a10 + a11) + (a12 + a13);
        pa += __shfl_xor(pa, 32, 64);               // combine k-halves
        pb += __shfl_xor(pb, 32, 64);
        const float q0 = tanh_f(fmaf(xt, vj0, cj0) + pa);
        const float q1 = tanh_f(fmaf(xt, vj1, cj1) + pb);
        if (s == 0) { q_lds[g][n0] = q0; q_lds[g][n1] = q1; }
        // own-wave write->read: DS ops from one wave are processed in order

        // ---- stage 2: z = q * sigmoid(q @ ew^T + eb), 2 outputs ----
        float e00 = 0, e01 = 0, e02 = 0, e03 = 0;
        float e10 = 0, e11 = 0, e12 = 0, e13 = 0;
        {
            float4 v0 = qp[0], v1 = qp[1], v2 = qp[2], v3 = qp[3];
            float4 v4 = qp[4], v5 = qp[5], v6 = qp[6], v7 = qp[7];
            dot4(we00, v0, e00, e01, e02, e03); dot4(we10, v0, e10, e11, e12, e13);
            dot4(we01, v1, e00, e01, e02, e03); dot4(we11, v1, e10, e11, e12, e13);
            dot4(we02, v2, e00, e01, e02, e03); dot4(we12, v2, e10, e11, e12, e13);
            dot4(we03, v3, e00, e01, e02, e03); dot4(we13, v3, e10, e11, e12, e13);
            dot4(we04, v4, e00, e01, e02, e03); dot4(we14, v4, e10, e11, e12, e13);
            dot4(we05, v5, e00, e01, e02, e03); dot4(we15, v5, e10, e11, e12, e13);
            dot4(we06, v6, e00, e01, e02, e03); dot4(we16, v6, e10, e11, e12, e13);
            dot4(we07, v7, e00, e01, e02, e03); dot4(we17, v7, e10, e11, e12, e13);
        }
        float pe0 = (e00 + e01) + (e02 + e03);
        float pe1 = (e10 + e11) + (e12 + e13);
        pe0 += __shfl_xor(pe0, 32, 64);
        pe1 += __shfl_xor(pe1, 32, 64);
        const float z0 = q0 * sigmoid_f(pe0 + ebj0);
        const float z1 = q1 * sigmoid_f(pe1 + ebj1);
        const float act0 = (g == 2) ? tanh_f(z0) : sigmoid_f(z0);
        const float act1 = (g == 2) ? tanh_f(z1) : sigmoid_f(z1);
        if (s == 0) {
            acts_t[t & 1][n0][g] = act0;
            acts_t[t & 1][n1][g] = act1;
        }
        __syncthreads();                            // the ONLY barrier per step

        // ---- cell update for np, redundantly on all 4 waves ----
        const float4 av = *(const float4*)&acts_t[t & 1][np][0];  // f,i,u,o
        cx = fmaf(av.x, cx, av.y * av.z);
        const float h = av.w * tanh_f(cx);
        h_lds[g][np] = h;                           // own-wave copy for stage 1
        if (g == 0) hist[t * 65 + np] = h;
    }
    __syncthreads();  // hist complete

    // fused classifier: T_*NC_ = 1280 outputs over 256 threads
#pragma unroll
    for (int j = 0; j < 5; j++) {
        const int o = j * 256 + tid;
        const int r = o / 10;
        const int c = o - r * 10;
        float sacc = cwts[NC_ * 65 + c];
#pragma unroll 16
        for (int k = 0; k < 64; k++)
            sacc = fmaf(hist[r * 65 + k], cwts[c * 65 + k], sacc);
        out[((size_t)r * B_ + b) * NC_ + c] = sacc;
    }
}

// ---------------------------------------------------------------------------
extern "C" void kernel_launch(void* const* d_in, const int* in_sizes, int n_in,
                              void* d_out, int out_size, void* d_ws, size_t ws_size,
                              hipStream_t stream) {
    const float* images = (const float*)d_in[0];
    const float* thr    = (const float*)d_in[1];
    const float* convw  = (const float*)d_in[2];
    const float* convb  = (const float*)d_in[3];
    const float* fcw[4]; const float* fcb[4]; const float* lw[4]; const float* lb[4];
    const float* ew[4];  const float* eb[4];
    for (int g = 0; g < 4; g++) {
        int base = 4 + g * 6;
        fcw[g] = (const float*)d_in[base + 0];
        fcb[g] = (const float*)d_in[base + 1];
        lw[g]  = (const float*)d_in[base + 2];
        lb[g]  = (const float*)d_in[base + 3];
        ew[g]  = (const float*)d_in[base + 4];
        eb[g]  = (const float*)d_in[base + 5];
    }
    const float* clsw = (const float*)d_in[28];
    const float* clsb = (const float*)d_in[29];

    float* ws   = (float*)d_ws;
    float* feat = ws;            // 8192 floats
    float* Aall = ws + 8192;     // 16384 floats
    float* Vall = ws + 24576;    // 256
    float* Call = ws + 24832;    // 256

    conv_feat<<<8192, 256, 0, stream>>>(images, convw, convb, thr, feat);

    FuseArgs fa;
    for (int g = 0; g < 4; g++) {
        fa.fcw[g] = fcw[g]; fa.fcb[g] = fcb[g];
        fa.lw[g] = lw[g];   fa.lb[g] = lb[g];
    }
    fuse_kernel<<<4, 256, 0, stream>>>(fa, Aall, Vall, Call);

    recur<<<B_, 256, 0, stream>>>(feat, Aall, Vall, Call,
                                  ew[0], eb[0], ew[1], eb[1],
                                  ew[2], eb[2], ew[3], eb[3],
                                  clsw, clsb, (float*)d_out);
}